// Round 3
// baseline (157.579 us; speedup 1.0000x reference)
//
#include <hip/hip_runtime.h>
#include <hip/hip_bf16.h>

// Problem geometry (fixed by reference config)
#define IN_F   4096
#define OUT_F  12288
#define OUT_PG 4096
#define M_ROWS 1024     // 2*512
#define R2     32       // GROUPS * R = 2*16

// ---------------- Kernel A: T[m][r32] = sum_k x[m][k] * wA[r32][k] ----------------
// Grid: 256 blocks x 512 threads. Block owns 4 rows, full K (no atomics).
// Thread t: kq = t>>7 (k-quarter), rowl = (t>>5)&3, r = t&31.
// Each thread: 1024-element dot (256 float4 iters). 4-way LDS reduce, then
// threads 0..127 store T (contiguous 512B per block).
__global__ __launch_bounds__(512) void lora_a_kernel(
    const float* __restrict__ x, const float* __restrict__ wA,
    float* __restrict__ T) {
  const int t = threadIdx.x;
  const int rbase = blockIdx.x * 4;
  const int kq   = t >> 7;          // 0..3
  const int rowl = (t >> 5) & 3;    // 0..3
  const int r    = t & 31;          // 0..31

  const float* __restrict__ xp = x  + (rbase + rowl) * IN_F + kq * 1024;
  const float* __restrict__ ap = wA + r * IN_F            + kq * 1024;

  float acc = 0.f;
#pragma unroll 8
  for (int i = 0; i < 256; ++i) {
    const float4 xv = *reinterpret_cast<const float4*>(&xp[i * 4]);
    const float4 av = *reinterpret_cast<const float4*>(&ap[i * 4]);
    acc += xv.x * av.x + xv.y * av.y + xv.z * av.z + xv.w * av.w;
  }

  __shared__ float red[512];
  red[t] = acc;
  __syncthreads();
  if (t < 128) {
    // t = rowl*32 + r ; T layout: (rbase+rowl)*32 + r = rbase*32 + t
    T[rbase * R2 + t] = red[t] + red[t + 128] + red[t + 256] + red[t + 384];
  }
}

// ---------------- Kernel B: out[m][col] = sum_r T[m][g*16+r] * wB[(g*4096+j)*16+r] ----
// Grid: (48 col-blocks x 32 row-blocks), 256 threads.
// Block tile: 32 rows x 256 cols. outblk = bx>>4 in {0,1,2}; outblk==1 -> zeros.
// Thread: cq = t&63 (4 consecutive cols), rowg = t>>6; 8 rows x 4 cols each.
// T tile staged in LDS (all lanes read same addr per row -> broadcast, free).
__global__ __launch_bounds__(256) void lora_b_kernel(
    const float* __restrict__ T, const float* __restrict__ wB,
    float* __restrict__ out) {
  const int t = threadIdx.x;
  const int bx = blockIdx.x;          // 0..47
  const int by = blockIdx.y;          // 0..31
  const int cbase = bx << 8;          // 256 cols per block
  const int rbase = by << 5;          // 32 rows per block
  const int outblk = bx >> 4;         // 0,1,2
  const int cq = t & 63;
  const int rowg = t >> 6;            // wave id (wave-uniform)
  const int col = cbase + cq * 4;

  if (outblk == 1) {
    const float4 z = {0.f, 0.f, 0.f, 0.f};
#pragma unroll
    for (int rr = 0; rr < 8; ++rr) {
      const int row = rbase + rowg * 8 + rr;
      *reinterpret_cast<float4*>(&out[row * OUT_F + col]) = z;
    }
    return;
  }
  const int g = outblk >> 1;          // 0 -> group 0, 2 -> group 1

  __shared__ float Ts[32][16];
  if (t < 128) {
    const int row = t >> 2, q = t & 3;
    *reinterpret_cast<float4*>(&Ts[row][q * 4]) =
        *reinterpret_cast<const float4*>(&T[(rbase + row) * R2 + g * 16 + q * 4]);
  }
  __syncthreads();

  const int j = col - ((outblk == 2) ? 8192 : 0);   // within-group col
  const float* __restrict__ Bp = &wB[(g * OUT_PG + j) * 16];

  // 4 cols x 16 r of B: 256B contiguous per thread (L2-resident).
  float4 B[4][4];
#pragma unroll
  for (int c = 0; c < 4; ++c)
#pragma unroll
    for (int q = 0; q < 4; ++q)
      B[c][q] = *reinterpret_cast<const float4*>(&Bp[c * 16 + q * 4]);

#pragma unroll
  for (int rr = 0; rr < 8; ++rr) {
    const int rowl = rowg * 8 + rr;
    float4 tv[4];
#pragma unroll
    for (int q = 0; q < 4; ++q)
      tv[q] = *reinterpret_cast<const float4*>(&Ts[rowl][q * 4]);
    float4 accv;
    float* accp = reinterpret_cast<float*>(&accv);
#pragma unroll
    for (int c = 0; c < 4; ++c) {
      float s = 0.f;
#pragma unroll
      for (int q = 0; q < 4; ++q) {
        s += tv[q].x * B[c][q].x + tv[q].y * B[c][q].y +
             tv[q].z * B[c][q].z + tv[q].w * B[c][q].w;
      }
      accp[c] = s;
    }
    *reinterpret_cast<float4*>(&out[(rbase + rowl) * OUT_F + col]) = accv;
  }
}

extern "C" void kernel_launch(void* const* d_in, const int* in_sizes, int n_in,
                              void* d_out, int out_size, void* d_ws, size_t ws_size,
                              hipStream_t stream) {
  const float* x  = (const float*)d_in[0];   // (2,512,4096) f32
  const float* wA = (const float*)d_in[1];   // (32,4096) f32
  const float* wB = (const float*)d_in[2];   // (8192,16) f32
  float* out = (float*)d_out;                // (2,512,12288) f32
  float* T   = (float*)d_ws;                 // (1024,32) f32 scratch

  lora_a_kernel<<<dim3(M_ROWS / 4), 512, 0, stream>>>(x, wA, T);
  lora_b_kernel<<<dim3(OUT_F / 256, M_ROWS / 32), 256, 0, stream>>>(T, wB, out);
}

// Round 4
// 131.133 us; speedup vs baseline: 1.2017x; 1.2017x over previous
//
#include <hip/hip_runtime.h>
#include <hip/hip_bf16.h>

// Problem geometry (fixed by reference config)
#define IN_F   4096
#define OUT_F  12288
#define OUT_PG 4096
#define M_ROWS 1024     // 2*512
#define R2     32       // GROUPS * R = 2*16
#define KSPLIT 4        // k-split factor for kernel A (partials in ws)

// ---------------- Kernel A: Tpart[ks][m][r] = sum_{k in slice ks} x[m][k]*wA[r][k] ----
// Grid: (KSPLIT=4, M_ROWS/4=256) x 256 threads. Wave w handles row rbase+w.
// Lane l covers k-offsets {kb + s*256 + l*4 : s=0..3} (all loads wave-contiguous 1KB).
// 32 independent acc chains per lane; butterfly tree-reduce (31 shfls) puts
// r=l&31 in lane l; one coalesced 128B store per wave. No atomics, no memset.
__global__ __launch_bounds__(256, 4) void lora_a_kernel(
    const float* __restrict__ x, const float* __restrict__ wA,
    float* __restrict__ Tpart) {
  const int t = threadIdx.x;
  const int l = t & 63;
  const int w = t >> 6;                  // wave id -> row within group
  const int ks = blockIdx.x;             // 0..3
  const int row = blockIdx.y * 4 + w;
  const int kb = ks * (IN_F / KSPLIT);   // 1024 k per slice

  const float* __restrict__ xp = x  + row * IN_F + kb + l * 4;
  const float* __restrict__ ap = wA + kb + l * 4;

  float4 xv[4];
#pragma unroll
  for (int s = 0; s < 4; ++s)
    xv[s] = *reinterpret_cast<const float4*>(&xp[s * 256]);

  float acc[32];
#pragma unroll
  for (int r = 0; r < 32; ++r) acc[r] = 0.f;

#pragma unroll
  for (int s = 0; s < 4; ++s) {
#pragma unroll
    for (int r = 0; r < 32; ++r) {
      const float4 av = *reinterpret_cast<const float4*>(&ap[r * IN_F + s * 256]);
      acc[r] += xv[s].x * av.x + xv[s].y * av.y + xv[s].z * av.z + xv[s].w * av.w;
    }
  }

  // Tree-reduce 32 partials across 64 lanes. After the 5 masked steps lane l
  // holds r = l&31 summed over its 32-lane half; final xor-32 merges halves.
#pragma unroll
  for (int m = 16; m >= 1; m >>= 1) {
#pragma unroll
    for (int i = 0; i < m; ++i) {
      const float a = acc[i], b = acc[i + m];
      const float mine   = (l & m) ? b : a;
      const float theirs = (l & m) ? a : b;
      acc[i] = mine + __shfl_xor(theirs, m, 64);
    }
  }
  const float v = acc[0] + __shfl_xor(acc[0], 32, 64);
  if (l < 32)
    Tpart[(ks * M_ROWS + row) * R2 + l] = v;
}

// ---------------- Kernel B: out[m][col] = sum_r T[m][g*16+r] * wB[(g*4096+j)*16+r] ----
// Structure unchanged from round 3 (for clean attribution) except the T-tile
// staging now sums the KSPLIT partials.
__global__ __launch_bounds__(256) void lora_b_kernel(
    const float* __restrict__ Tpart, const float* __restrict__ wB,
    float* __restrict__ out) {
  const int t = threadIdx.x;
  const int bx = blockIdx.x;          // 0..47
  const int by = blockIdx.y;          // 0..31
  const int cbase = bx << 8;          // 256 cols per block
  const int rbase = by << 5;          // 32 rows per block
  const int outblk = bx >> 4;         // 0,1,2
  const int cq = t & 63;
  const int rowg = t >> 6;            // wave id (wave-uniform)
  const int col = cbase + cq * 4;

  if (outblk == 1) {
    const float4 z = {0.f, 0.f, 0.f, 0.f};
#pragma unroll
    for (int rr = 0; rr < 8; ++rr) {
      const int row = rbase + rowg * 8 + rr;
      *reinterpret_cast<float4*>(&out[row * OUT_F + col]) = z;
    }
    return;
  }
  const int g = outblk >> 1;          // 0 -> group 0, 2 -> group 1

  __shared__ float Ts[32][16];
  if (t < 128) {
    const int row = t >> 2, q = t & 3;
    float4 s = {0.f, 0.f, 0.f, 0.f};
#pragma unroll
    for (int ks = 0; ks < KSPLIT; ++ks) {
      const float4 vv = *reinterpret_cast<const float4*>(
          &Tpart[(ks * M_ROWS + rbase + row) * R2 + g * 16 + q * 4]);
      s.x += vv.x; s.y += vv.y; s.z += vv.z; s.w += vv.w;
    }
    *reinterpret_cast<float4*>(&Ts[row][q * 4]) = s;
  }
  __syncthreads();

  const int j = col - ((outblk == 2) ? 8192 : 0);   // within-group col
  const float* __restrict__ Bp = &wB[(g * OUT_PG + j) * 16];

  // 4 cols x 16 r of B: 256B contiguous per thread (L2-resident).
  float4 B[4][4];
#pragma unroll
  for (int c = 0; c < 4; ++c)
#pragma unroll
    for (int q = 0; q < 4; ++q)
      B[c][q] = *reinterpret_cast<const float4*>(&Bp[c * 16 + q * 4]);

#pragma unroll
  for (int rr = 0; rr < 8; ++rr) {
    const int rowl = rowg * 8 + rr;
    float4 tv[4];
#pragma unroll
    for (int q = 0; q < 4; ++q)
      tv[q] = *reinterpret_cast<const float4*>(&Ts[rowl][q * 4]);
    float4 accv;
    float* accp = reinterpret_cast<float*>(&accv);
#pragma unroll
    for (int c = 0; c < 4; ++c) {
      float s = 0.f;
#pragma unroll
      for (int q = 0; q < 4; ++q) {
        s += tv[q].x * B[c][q].x + tv[q].y * B[c][q].y +
             tv[q].z * B[c][q].z + tv[q].w * B[c][q].w;
      }
      accp[c] = s;
    }
    *reinterpret_cast<float4*>(&out[(rbase + rowl) * OUT_F + col]) = accv;
  }
}

extern "C" void kernel_launch(void* const* d_in, const int* in_sizes, int n_in,
                              void* d_out, int out_size, void* d_ws, size_t ws_size,
                              hipStream_t stream) {
  const float* x  = (const float*)d_in[0];   // (2,512,4096) f32
  const float* wA = (const float*)d_in[1];   // (32,4096) f32
  const float* wB = (const float*)d_in[2];   // (8192,16) f32
  float* out = (float*)d_out;                // (2,512,12288) f32
  float* Tpart = (float*)d_ws;               // (KSPLIT,1024,32) f32 = 512 KB scratch

  lora_a_kernel<<<dim3(KSPLIT, M_ROWS / 4), 256, 0, stream>>>(x, wA, Tpart);
  lora_b_kernel<<<dim3(OUT_F / 256, M_ROWS / 32), 256, 0, stream>>>(Tpart, wB, out);
}

// Round 7
// 98.078 us; speedup vs baseline: 1.6067x; 1.3370x over previous
//
#include <hip/hip_runtime.h>
#include <hip/hip_bf16.h>

// Problem geometry (fixed by reference config)
#define IN_F   4096
#define OUT_F  12288
#define OUT_PG 4096
#define M_ROWS 1024     // 2*512
#define R2     32       // GROUPS * R = 2*16

// ---------------- Kernel A: Tpart[ks][m][r] = sum_{k in slice} x[m][k]*wA[r][k] ----
// Grid: (KS, 128) x 256 thr. Block = 4 waves x 2 rows = 8 rows, k-slice IN_F/KS.
// Slice processed in 256-k chunks: stage wA chunk (32 KB) in LDS (coalesced),
// inner loop reads it as benign-consecutive ds_read_b128 (1KB/wave-instr) with
// 2 rows x 4 FMA per read. Butterfly tree-reduce -> 256B coalesced store/wave.
template <int KS>
__global__ __launch_bounds__(256) void lora_a_kernel(
    const float* __restrict__ x, const float* __restrict__ wA,
    float* __restrict__ Tpart) {
  constexpr int SLICE  = IN_F / KS;
  constexpr int CHUNKS = SLICE / 256;
  __shared__ float As[R2 * 256];        // 32 KB

  const int t = threadIdx.x;
  const int l = t & 63;
  const int w = t >> 6;                 // wave id
  const int ks = blockIdx.x;
  const int row0 = blockIdx.y * 8 + w * 2;
  const int kb = ks * SLICE;

  float acc[2][32];
#pragma unroll
  for (int m = 0; m < 2; ++m)
#pragma unroll
    for (int r = 0; r < 32; ++r) acc[m][r] = 0.f;

  for (int c = 0; c < CHUNKS; ++c) {
    const int kc = kb + c * 256;
    if (c) __syncthreads();
    // Stage 32x256 wA chunk: flat f = r*256+kk, 8 float4 per thread, coalesced.
#pragma unroll
    for (int i = 0; i < 8; ++i) {
      const int f = t * 4 + i * 1024;
      const int r = f >> 8, kk = f & 255;
      *reinterpret_cast<float4*>(&As[f]) =
          *reinterpret_cast<const float4*>(&wA[r * IN_F + kc + kk]);
    }
    __syncthreads();

    float4 xv[2];
#pragma unroll
    for (int m = 0; m < 2; ++m)
      xv[m] = *reinterpret_cast<const float4*>(&x[(row0 + m) * IN_F + kc + l * 4]);

#pragma unroll
    for (int r = 0; r < 32; ++r) {
      const float4 av = *reinterpret_cast<const float4*>(&As[r * 256 + l * 4]);
      acc[0][r] += xv[0].x * av.x + xv[0].y * av.y + xv[0].z * av.z + xv[0].w * av.w;
      acc[1][r] += xv[1].x * av.x + xv[1].y * av.y + xv[1].z * av.z + xv[1].w * av.w;
    }
  }

  // Tree-reduce 32 partials across 64 lanes (per row). After the masked steps
  // + xor-32 merge, every lane holds the full sum for r = l&31.
  float v[2];
#pragma unroll
  for (int m2 = 0; m2 < 2; ++m2) {
#pragma unroll
    for (int m = 16; m >= 1; m >>= 1) {
#pragma unroll
      for (int i = 0; i < m; ++i) {
        const float a = acc[m2][i], b = acc[m2][i + m];
        const float mine   = (l & m) ? b : a;
        const float theirs = (l & m) ? a : b;
        acc[m2][i] = mine + __shfl_xor(theirs, m, 64);
      }
    }
    v[m2] = acc[m2][0] + __shfl_xor(acc[m2][0], 32, 64);
  }
  // lanes 0..31 -> row0, lanes 32..63 -> row0+1; 256B contiguous per wave.
  const float outv = (l < 32) ? v[0] : v[1];
  Tpart[(ks * M_ROWS + row0 + (l >> 5)) * R2 + (l & 31)] = outv;
}

// ---------------- Kernel B: out[m][col] = sum_r T[m][g*16+r] * wB[col][r] ----------
// Grid: (48, 8) x 256 thr. Block tile 128 rows x 256 cols. outblk==1 -> zeros.
// wB tile staged TRANSPOSED in LDS (coalesced global f4 reads, 2-way-conflict
// scalar writes at stride 260); per-thread B regs via benign-consecutive b128.
// T tile in LDS, broadcast reads. Coalesced f4 stores.
// FIX vs round 6: wB staging must use the WITHIN-GROUP column (jbase), not the
// global output column — outblk==2 read 8192 rows past the end of wB before.
template <int KS>
__global__ __launch_bounds__(256) void lora_b_kernel(
    const float* __restrict__ Tpart, const float* __restrict__ wB,
    float* __restrict__ out) {
  const int t = threadIdx.x;
  const int bx = blockIdx.x;           // 0..47
  const int by = blockIdx.y;           // 0..7
  const int cbase = bx << 8;
  const int rbase = by << 7;           // 128 rows
  const int outblk = bx >> 4;          // 0,1,2
  const int cq = t & 63;               // col quad
  const int rowg = t >> 6;             // wave id (uniform)
  const int col = cbase + cq * 4;

  if (outblk == 1) {
    const float4 z = {0.f, 0.f, 0.f, 0.f};
#pragma unroll
    for (int rr = 0; rr < 32; ++rr) {
      const int row = rbase + rowg * 32 + rr;
      *reinterpret_cast<float4*>(&out[row * OUT_F + col]) = z;
    }
    return;
  }
  const int g = outblk >> 1;
  const int jbase = cbase - ((outblk == 2) ? 2 * OUT_PG : 0);  // within-group col base

  __shared__ float BsT[16 * 260];      // [r][col], stride 260 (pad 4)
  __shared__ float Ts[128 * 16];

  // Stage wB^T: 1024 f4, 4 per thread; global reads perfectly coalesced.
#pragma unroll
  for (int i = 0; i < 4; ++i) {
    const int idx = t + i * 256;
    const int c = idx >> 2, r0 = (idx & 3) * 4;
    const float4 v = *reinterpret_cast<const float4*>(
        &wB[(g * OUT_PG + jbase + c) * 16 + r0]);
    BsT[(r0 + 0) * 260 + c] = v.x;
    BsT[(r0 + 1) * 260 + c] = v.y;
    BsT[(r0 + 2) * 260 + c] = v.z;
    BsT[(r0 + 3) * 260 + c] = v.w;
  }
  // Stage T tile with KS-partial sum: 512 f4, 2 per thread.
#pragma unroll
  for (int i = 0; i < 2; ++i) {
    const int idx = t + i * 256;
    const int row = idx >> 2, q = idx & 3;
    float4 s = {0.f, 0.f, 0.f, 0.f};
#pragma unroll
    for (int ks = 0; ks < KS; ++ks) {
      const float4 vv = *reinterpret_cast<const float4*>(
          &Tpart[(ks * M_ROWS + rbase + row) * R2 + g * 16 + q * 4]);
      s.x += vv.x; s.y += vv.y; s.z += vv.z; s.w += vv.w;
    }
    *reinterpret_cast<float4*>(&Ts[row * 16 + q * 4]) = s;
  }
  __syncthreads();

  // Per-thread B: brow[r] = B values of this thread's 4 cols at rank r.
  float4 brow[16];
#pragma unroll
  for (int r = 0; r < 16; ++r)
    brow[r] = *reinterpret_cast<const float4*>(&BsT[r * 260 + cq * 4]);

#pragma unroll
  for (int rr = 0; rr < 32; ++rr) {
    const int rowl = rowg * 32 + rr;
    float ts[16];
#pragma unroll
    for (int q = 0; q < 4; ++q)
      *reinterpret_cast<float4*>(&ts[q * 4]) =
          *reinterpret_cast<const float4*>(&Ts[rowl * 16 + q * 4]);  // broadcast
    float a0 = 0.f, a1 = 0.f, a2 = 0.f, a3 = 0.f;
#pragma unroll
    for (int r = 0; r < 16; ++r) {
      a0 += ts[r] * brow[r].x;
      a1 += ts[r] * brow[r].y;
      a2 += ts[r] * brow[r].z;
      a3 += ts[r] * brow[r].w;
    }
    const float4 accv = {a0, a1, a2, a3};
    *reinterpret_cast<float4*>(&out[(rbase + rowl) * OUT_F + col]) = accv;
  }
}

extern "C" void kernel_launch(void* const* d_in, const int* in_sizes, int n_in,
                              void* d_out, int out_size, void* d_ws, size_t ws_size,
                              hipStream_t stream) {
  const float* x  = (const float*)d_in[0];   // (2,512,4096) f32
  const float* wA = (const float*)d_in[1];   // (32,4096) f32
  const float* wB = (const float*)d_in[2];   // (8192,16) f32
  float* out = (float*)d_out;                // (2,512,12288) f32
  float* Tpart = (float*)d_ws;               // (KS,1024,32) f32

  const size_t ws_elems = ws_size / sizeof(float);
  if (ws_elems >= (size_t)16 * M_ROWS * R2) {
    lora_a_kernel<16><<<dim3(16, M_ROWS / 8), 256, 0, stream>>>(x, wA, Tpart);
    lora_b_kernel<16><<<dim3(OUT_F / 256, M_ROWS / 128), 256, 0, stream>>>(Tpart, wB, out);
  } else if (ws_elems >= (size_t)8 * M_ROWS * R2) {
    lora_a_kernel<8><<<dim3(8, M_ROWS / 8), 256, 0, stream>>>(x, wA, Tpart);
    lora_b_kernel<8><<<dim3(OUT_F / 256, M_ROWS / 128), 256, 0, stream>>>(Tpart, wB, out);
  } else {
    lora_a_kernel<4><<<dim3(4, M_ROWS / 8), 256, 0, stream>>>(x, wA, Tpart);
    lora_b_kernel<4><<<dim3(OUT_F / 256, M_ROWS / 128), 256, 0, stream>>>(Tpart, wB, out);
  }
}

// Round 8
// 94.589 us; speedup vs baseline: 1.6659x; 1.0369x over previous
//
#include <hip/hip_runtime.h>
#include <hip/hip_bf16.h>

// Problem geometry (fixed by reference config)
#define IN_F   4096
#define OUT_F  12288
#define OUT_PG 4096
#define M_ROWS 1024     // 2*512
#define R2     32       // GROUPS * R = 2*16

// ---------------- Kernel A: Tpart[ks][m][r] = sum_{k in slice} x[m][k]*wA[r][k] ----
// Grid: (KS, 128) x 256 thr. Block = 4 waves x 2 rows = 8 rows, k-slice IN_F/KS.
// ALSO zero-fills its share of the disabled middle output block (out cols
// 4096..8192): 8 rows x (4096/KS) cols per block, issued FIRST so the stores
// drain in the background under the compute (A has idle write BW).
// Slice processed in 256-k chunks: stage wA chunk (32 KB) in LDS (coalesced),
// inner loop reads it as benign-consecutive ds_read_b128 (1KB/wave-instr) with
// 2 rows x 4 FMA per read. Butterfly tree-reduce -> 256B coalesced store/wave.
template <int KS>
__global__ __launch_bounds__(256) void lora_a_kernel(
    const float* __restrict__ x, const float* __restrict__ wA,
    float* __restrict__ Tpart, float* __restrict__ out) {
  constexpr int SLICE  = IN_F / KS;
  constexpr int CHUNKS = SLICE / 256;
  constexpr int ZC     = OUT_PG / KS;       // zero-fill cols per block
  __shared__ float As[R2 * 256];            // 32 KB

  const int t = threadIdx.x;
  const int l = t & 63;
  const int w = t >> 6;                     // wave id
  const int ks = blockIdx.x;
  const int row0 = blockIdx.y * 8 + w * 2;
  const int kb = ks * SLICE;

  // Zero-fill share of the middle block: rows by*8..+8, cols OUT_PG+ks*ZC..+ZC.
  {
    const int zrow0 = blockIdx.y * 8;
    const int zcol0 = OUT_PG + ks * ZC;
    const float4 z = {0.f, 0.f, 0.f, 0.f};
#pragma unroll
    for (int i = 0; i < ZC / 128; ++i) {    // 8*ZC/4 f4 / 256 thr
      const int idx = t + i * 256;
      const int zr = idx / (ZC / 4);
      const int zc = (idx % (ZC / 4)) * 4;
      *reinterpret_cast<float4*>(&out[(zrow0 + zr) * OUT_F + zcol0 + zc]) = z;
    }
  }

  float acc[2][32];
#pragma unroll
  for (int m = 0; m < 2; ++m)
#pragma unroll
    for (int r = 0; r < 32; ++r) acc[m][r] = 0.f;

  for (int c = 0; c < CHUNKS; ++c) {
    const int kc = kb + c * 256;
    if (c) __syncthreads();
    // Stage 32x256 wA chunk: flat f = r*256+kk, 8 float4 per thread, coalesced.
#pragma unroll
    for (int i = 0; i < 8; ++i) {
      const int f = t * 4 + i * 1024;
      const int r = f >> 8, kk = f & 255;
      *reinterpret_cast<float4*>(&As[f]) =
          *reinterpret_cast<const float4*>(&wA[r * IN_F + kc + kk]);
    }
    __syncthreads();

    float4 xv[2];
#pragma unroll
    for (int m = 0; m < 2; ++m)
      xv[m] = *reinterpret_cast<const float4*>(&x[(row0 + m) * IN_F + kc + l * 4]);

#pragma unroll
    for (int r = 0; r < 32; ++r) {
      const float4 av = *reinterpret_cast<const float4*>(&As[r * 256 + l * 4]);
      acc[0][r] += xv[0].x * av.x + xv[0].y * av.y + xv[0].z * av.z + xv[0].w * av.w;
      acc[1][r] += xv[1].x * av.x + xv[1].y * av.y + xv[1].z * av.z + xv[1].w * av.w;
    }
  }

  // Tree-reduce 32 partials across 64 lanes (per row). After the masked steps
  // + xor-32 merge, every lane holds the full sum for r = l&31.
  float v[2];
#pragma unroll
  for (int m2 = 0; m2 < 2; ++m2) {
#pragma unroll
    for (int m = 16; m >= 1; m >>= 1) {
#pragma unroll
      for (int i = 0; i < m; ++i) {
        const float a = acc[m2][i], b = acc[m2][i + m];
        const float mine   = (l & m) ? b : a;
        const float theirs = (l & m) ? a : b;
        acc[m2][i] = mine + __shfl_xor(theirs, m, 64);
      }
    }
    v[m2] = acc[m2][0] + __shfl_xor(acc[m2][0], 32, 64);
  }
  // lanes 0..31 -> row0, lanes 32..63 -> row0+1; 256B contiguous per wave.
  const float outv = (l < 32) ? v[0] : v[1];
  Tpart[(ks * M_ROWS + row0 + (l >> 5)) * R2 + (l & 31)] = outv;
}

// ---------------- Kernel B: out[m][col] = sum_r T[m][g*16+r] * wB[col][r] ----------
// Covers ONLY the two LoRA-enabled output blocks (middle block zeroed by A).
// Grid: (32, 32) x 256 thr = 1024 blocks (4/CU). Block tile 32 rows x 256 cols.
// bx<16 -> group 0 (out cols 0..4096); bx>=16 -> group 1 (out cols 8192..12288).
// wB tile staged TRANSPOSED in LDS; T tile (KS-partial sum) in LDS, broadcast
// reads; per-thread 8 rows x 4 cols, coalesced f4 stores.
template <int KS>
__global__ __launch_bounds__(256) void lora_b_kernel(
    const float* __restrict__ Tpart, const float* __restrict__ wB,
    float* __restrict__ out) {
  const int t = threadIdx.x;
  const int bx = blockIdx.x;            // 0..31
  const int by = blockIdx.y;            // 0..31
  const int g = bx >> 4;                // 0,1
  const int jbase = (bx & 15) << 8;     // within-group col base
  const int colbase = g ? (2 * OUT_PG + jbase) : jbase;
  const int rbase = by << 5;            // 32 rows
  const int cq = t & 63;                // col quad
  const int rowg = t >> 6;              // wave id (uniform)

  __shared__ float BsT[16 * 260];       // [r][col], stride 260 (pad 4)
  __shared__ float Ts[32 * 16];

  // Stage wB^T: 256 cols x 16 r = 1024 f4, 4 per thread; coalesced global reads.
#pragma unroll
  for (int i = 0; i < 4; ++i) {
    const int idx = t + i * 256;
    const int c = idx >> 2, r0 = (idx & 3) * 4;
    const float4 v = *reinterpret_cast<const float4*>(
        &wB[(g * OUT_PG + jbase + c) * 16 + r0]);
    BsT[(r0 + 0) * 260 + c] = v.x;
    BsT[(r0 + 1) * 260 + c] = v.y;
    BsT[(r0 + 2) * 260 + c] = v.z;
    BsT[(r0 + 3) * 260 + c] = v.w;
  }
  // Stage T tile with KS-partial sum: 32 rows x 4 f4 = 128 f4, threads 0..127.
  if (t < 128) {
    const int row = t >> 2, q = t & 3;
    float4 s = {0.f, 0.f, 0.f, 0.f};
#pragma unroll
    for (int ks = 0; ks < KS; ++ks) {
      const float4 vv = *reinterpret_cast<const float4*>(
          &Tpart[(ks * M_ROWS + rbase + row) * R2 + g * 16 + q * 4]);
      s.x += vv.x; s.y += vv.y; s.z += vv.z; s.w += vv.w;
    }
    *reinterpret_cast<float4*>(&Ts[row * 16 + q * 4]) = s;
  }
  __syncthreads();

  // Per-thread B: brow[r] = B values of this thread's 4 cols at rank r.
  float4 brow[16];
#pragma unroll
  for (int r = 0; r < 16; ++r)
    brow[r] = *reinterpret_cast<const float4*>(&BsT[r * 260 + cq * 4]);

#pragma unroll
  for (int rr = 0; rr < 8; ++rr) {
    const int rowl = rowg * 8 + rr;
    float ts[16];
#pragma unroll
    for (int q = 0; q < 4; ++q)
      *reinterpret_cast<float4*>(&ts[q * 4]) =
          *reinterpret_cast<const float4*>(&Ts[rowl * 16 + q * 4]);  // broadcast
    float a0 = 0.f, a1 = 0.f, a2 = 0.f, a3 = 0.f;
#pragma unroll
    for (int r = 0; r < 16; ++r) {
      a0 += ts[r] * brow[r].x;
      a1 += ts[r] * brow[r].y;
      a2 += ts[r] * brow[r].z;
      a3 += ts[r] * brow[r].w;
    }
    const float4 accv = {a0, a1, a2, a3};
    *reinterpret_cast<float4*>(&out[(rbase + rowl) * OUT_F + colbase + cq * 4]) = accv;
  }
}

extern "C" void kernel_launch(void* const* d_in, const int* in_sizes, int n_in,
                              void* d_out, int out_size, void* d_ws, size_t ws_size,
                              hipStream_t stream) {
  const float* x  = (const float*)d_in[0];   // (2,512,4096) f32
  const float* wA = (const float*)d_in[1];   // (32,4096) f32
  const float* wB = (const float*)d_in[2];   // (8192,16) f32
  float* out = (float*)d_out;                // (2,512,12288) f32
  float* Tpart = (float*)d_ws;               // (KS,1024,32) f32

  const size_t ws_elems = ws_size / sizeof(float);
  if (ws_elems >= (size_t)16 * M_ROWS * R2) {
    lora_a_kernel<16><<<dim3(16, M_ROWS / 8), 256, 0, stream>>>(x, wA, Tpart, out);
    lora_b_kernel<16><<<dim3(32, M_ROWS / 32), 256, 0, stream>>>(Tpart, wB, out);
  } else if (ws_elems >= (size_t)8 * M_ROWS * R2) {
    lora_a_kernel<8><<<dim3(8, M_ROWS / 8), 256, 0, stream>>>(x, wA, Tpart, out);
    lora_b_kernel<8><<<dim3(32, M_ROWS / 32), 256, 0, stream>>>(Tpart, wB, out);
  } else {
    lora_a_kernel<4><<<dim3(4, M_ROWS / 8), 256, 0, stream>>>(x, wA, Tpart, out);
    lora_b_kernel<4><<<dim3(32, M_ROWS / 32), 256, 0, stream>>>(Tpart, wB, out);
  }
}